// Round 11
// baseline (240.014 us; speedup 1.0000x reference)
//
#include <hip/hip_runtime.h>
#include <math.h>

#define NN 50000
#define KK 16
#define FIN 140
#define HH 8
#define HID 128

typedef __attribute__((ext_vector_type(8))) short short8;   // 8 bf16 = 4 VGPRs
typedef __attribute__((ext_vector_type(4))) float f32x4;    // MFMA acc

__device__ inline unsigned short f2bf(float f) {            // RNE fp32->bf16
  unsigned int u = __float_as_uint(f);
  return (unsigned short)((u + 0x7fffu + ((u >> 16) & 1u)) >> 16);
}
__device__ inline float bf2f(unsigned short h) {
  return __uint_as_float(((unsigned int)h) << 16);
}

// Build W^T A-operand fragment tables (hi/lo bf16 split) for pca_w and both Ws.
// A-layout for mfma_f32_16x16x32_bf16: lane L holds A[m=(L&15)][k=(L>>4)*8+j];
// m_global = t*16+(L&15) (out col), k = c*32+(L>>4)*8+j, value = W[k][m_global].
// frags layout (shorts): [pcaH 20480][pcaL 20480][W0H 16384][W0L 16384][W1H 16384][W1L 16384]
__global__ __launch_bounds__(256) void prep_kernel(
    const float* __restrict__ pca_w, const float* __restrict__ Ws,
    unsigned short* __restrict__ frags) {
  const int gid = blockIdx.x * 256 + threadIdx.x;   // 208*256 = 53248 exact
  const float* W; int K; unsigned short *dh, *dl; int tid;
  if (gid < 20480)      { W = pca_w;          K = FIN; dh = frags;                 dl = dh + 20480; tid = gid; }
  else if (gid < 36864) { W = Ws;             K = HID; dh = frags + 40960;         dl = dh + 16384; tid = gid - 20480; }
  else                  { W = Ws + HID * HID; K = HID; dh = frags + 40960 + 32768; dl = dh + 16384; tid = gid - 36864; }
  const int j = tid & 7, L = (tid >> 3) & 63, ct = tid >> 9, t = ct & 7, c = ct >> 3;
  const int k = c * 32 + (L >> 4) * 8 + j;
  const int col = t * 16 + (L & 15);
  const float v = (k < K) ? W[(size_t)k * HID + col] : 0.f;
  const unsigned short h = f2bf(v);
  dh[tid] = h;
  dl[tid] = f2bf(v - bf2f(h));
}

// x = relu(feature @ pca_w + b) -> bf16. TWO 16-node tiles per wave; weight
// fragments loaded once and used for both tiles.
__global__ __launch_bounds__(64) void pca_mfma(
    const float* __restrict__ feat, const unsigned short* __restrict__ wfh,
    const unsigned short* __restrict__ wfl, const float* __restrict__ b,
    unsigned short* __restrict__ xbf) {
  const int lane = threadIdx.x;
  const int col = lane & 15, quad = lane >> 4;
  const int tile0 = blockIdx.x * 2;
  const int tile1 = tile0 + 1;
  const bool has1 = (tile1 < NN / 16);
  const int n0 = tile0 * 16, n1 = tile1 * 16;
  f32x4 acc0[8], acc1[8];
#pragma unroll
  for (int t = 0; t < 8; ++t) {
    acc0[t] = (f32x4){0.f, 0.f, 0.f, 0.f};
    acc1[t] = (f32x4){0.f, 0.f, 0.f, 0.f};
  }
  const float* brow0 = feat + (size_t)(n0 + col) * FIN + quad * 8;
  const float* brow1 = feat + (size_t)((has1 ? n1 : n0) + col) * FIN + quad * 8;
#pragma unroll
  for (int c = 0; c < 5; ++c) {
    float4 a0, a1, c0, c1;
    if (c < 4) {
      a0 = *(const float4*)(brow0 + c * 32);
      a1 = *(const float4*)(brow0 + c * 32 + 4);
      c0 = *(const float4*)(brow1 + c * 32);
      c1 = *(const float4*)(brow1 + c * 32 + 4);
    } else {  // chunk 4: k = 128 + quad*8 + j, valid only k < 140
      a0 = make_float4(0.f, 0.f, 0.f, 0.f); a1 = a0; c0 = a0; c1 = a0;
      if (quad == 0) {
        a0 = *(const float4*)(brow0 + 128); a1 = *(const float4*)(brow0 + 132);
        c0 = *(const float4*)(brow1 + 128); c1 = *(const float4*)(brow1 + 132);
      } else if (quad == 1) {
        a0 = *(const float4*)(brow0 + 128);
        c0 = *(const float4*)(brow1 + 128);
      }
    }
    short8 B0, B1;
    B0[0] = (short)f2bf(a0.x); B0[1] = (short)f2bf(a0.y);
    B0[2] = (short)f2bf(a0.z); B0[3] = (short)f2bf(a0.w);
    B0[4] = (short)f2bf(a1.x); B0[5] = (short)f2bf(a1.y);
    B0[6] = (short)f2bf(a1.z); B0[7] = (short)f2bf(a1.w);
    B1[0] = (short)f2bf(c0.x); B1[1] = (short)f2bf(c0.y);
    B1[2] = (short)f2bf(c0.z); B1[3] = (short)f2bf(c0.w);
    B1[4] = (short)f2bf(c1.x); B1[5] = (short)f2bf(c1.y);
    B1[6] = (short)f2bf(c1.z); B1[7] = (short)f2bf(c1.w);
#pragma unroll
    for (int t = 0; t < 8; ++t) {
      const short8 Ah = *(const short8*)(wfh + ((size_t)(c * 8 + t) * 64 + lane) * 8);
      const short8 Al = *(const short8*)(wfl + ((size_t)(c * 8 + t) * 64 + lane) * 8);
      acc0[t] = __builtin_amdgcn_mfma_f32_16x16x32_bf16(Al, B0, acc0[t], 0, 0, 0);
      acc0[t] = __builtin_amdgcn_mfma_f32_16x16x32_bf16(Ah, B0, acc0[t], 0, 0, 0);
      acc1[t] = __builtin_amdgcn_mfma_f32_16x16x32_bf16(Al, B1, acc1[t], 0, 0, 0);
      acc1[t] = __builtin_amdgcn_mfma_f32_16x16x32_bf16(Ah, B1, acc1[t], 0, 0, 0);
    }
  }
#pragma unroll
  for (int t = 0; t < 8; ++t) {
    const float4 bv = *(const float4*)(b + t * 16 + quad * 4);
    {
      const float v0 = fmaxf(acc0[t][0] + bv.x, 0.f);
      const float v1 = fmaxf(acc0[t][1] + bv.y, 0.f);
      const float v2 = fmaxf(acc0[t][2] + bv.z, 0.f);
      const float v3 = fmaxf(acc0[t][3] + bv.w, 0.f);
      uint2 pk;
      pk.x = (unsigned)f2bf(v0) | ((unsigned)f2bf(v1) << 16);
      pk.y = (unsigned)f2bf(v2) | ((unsigned)f2bf(v3) << 16);
      *(uint2*)&xbf[(size_t)(n0 + col) * HID + t * 16 + quad * 4] = pk;
    }
    if (has1) {
      const float v0 = fmaxf(acc1[t][0] + bv.x, 0.f);
      const float v1 = fmaxf(acc1[t][1] + bv.y, 0.f);
      const float v2 = fmaxf(acc1[t][2] + bv.z, 0.f);
      const float v3 = fmaxf(acc1[t][3] + bv.w, 0.f);
      uint2 pk;
      pk.x = (unsigned)f2bf(v0) | ((unsigned)f2bf(v1) << 16);
      pk.y = (unsigned)f2bf(v2) | ((unsigned)f2bf(v3) << 16);
      *(uint2*)&xbf[(size_t)(n1 + col) * HID + t * 16 + quad * 4] = pk;
    }
  }
}

// h = x@W + b; writes HEAD-MAJOR h table hm[8][N][16] (bf16) plus head-major
// logit tables sm[8][N], dm[8][N]. TWO tiles per wave.
__global__ __launch_bounds__(64) void proj_mfma(
    const unsigned short* __restrict__ xbf, const unsigned short* __restrict__ wfh,
    const unsigned short* __restrict__ wfl, const float* __restrict__ b,
    const float* __restrict__ asrc, const float* __restrict__ adst,
    unsigned short* __restrict__ hm, float* __restrict__ sm,
    float* __restrict__ dm) {
  const int lane = threadIdx.x;
  const int col = lane & 15, quad = lane >> 4;
  const int tile0 = blockIdx.x * 2;
  const int tile1 = tile0 + 1;
  const bool has1 = (tile1 < NN / 16);
  const int n0 = tile0 * 16, n1 = tile1 * 16;
  f32x4 acc0[8], acc1[8];
#pragma unroll
  for (int t = 0; t < 8; ++t) {
    acc0[t] = (f32x4){0.f, 0.f, 0.f, 0.f};
    acc1[t] = (f32x4){0.f, 0.f, 0.f, 0.f};
  }
  const unsigned short* brow0 = xbf + (size_t)(n0 + col) * HID + quad * 8;
  const unsigned short* brow1 = xbf + (size_t)((has1 ? n1 : n0) + col) * HID + quad * 8;
  short8 B0[4], B1[4];
#pragma unroll
  for (int c = 0; c < 4; ++c) {
    B0[c] = *(const short8*)(brow0 + c * 32);
    B1[c] = *(const short8*)(brow1 + c * 32);
  }
#pragma unroll
  for (int c = 0; c < 4; ++c) {
#pragma unroll
    for (int t = 0; t < 8; ++t) {
      const short8 Ah = *(const short8*)(wfh + ((size_t)(c * 8 + t) * 64 + lane) * 8);
      const short8 Al = *(const short8*)(wfl + ((size_t)(c * 8 + t) * 64 + lane) * 8);
      acc0[t] = __builtin_amdgcn_mfma_f32_16x16x32_bf16(Al, B0[c], acc0[t], 0, 0, 0);
      acc0[t] = __builtin_amdgcn_mfma_f32_16x16x32_bf16(Ah, B0[c], acc0[t], 0, 0, 0);
      acc1[t] = __builtin_amdgcn_mfma_f32_16x16x32_bf16(Al, B1[c], acc1[t], 0, 0, 0);
      acc1[t] = __builtin_amdgcn_mfma_f32_16x16x32_bf16(Ah, B1[c], acc1[t], 0, 0, 0);
    }
  }
  // lane holds node base+col, out-cols t*16+quad*4+r (head == t)
#pragma unroll
  for (int t = 0; t < 8; ++t) {
    const float4 bv = *(const float4*)(b + t * 16 + quad * 4);
    const float4 av = *(const float4*)(asrc + t * 16 + quad * 4);
    const float4 dv = *(const float4*)(adst + t * 16 + quad * 4);
#pragma unroll
    for (int p = 0; p < 2; ++p) {
      if (p == 1 && !has1) break;
      const f32x4& a = p ? acc1[t] : acc0[t];
      const int nb_ = p ? n1 : n0;
      const float v0 = a[0] + bv.x;
      const float v1 = a[1] + bv.y;
      const float v2 = a[2] + bv.z;
      const float v3 = a[3] + bv.w;
      uint2 pk;
      pk.x = (unsigned)f2bf(v0) | ((unsigned)f2bf(v1) << 16);
      pk.y = (unsigned)f2bf(v2) | ((unsigned)f2bf(v3) << 16);
      // head-major: hm[t][node][quad*4 .. quad*4+3]
      *(uint2*)&hm[((size_t)t * NN + nb_ + col) * 16 + quad * 4] = pk;
      float ps = v0 * av.x + v1 * av.y + v2 * av.z + v3 * av.w;
      float pd = v0 * dv.x + v1 * dv.y + v2 * dv.z + v3 * dv.w;
      ps += __shfl_xor(ps, 16); ps += __shfl_xor(ps, 32);
      pd += __shfl_xor(pd, 16); pd += __shfl_xor(pd, 32);
      if (quad == 0) sm[(size_t)t * NN + nb_ + col] = ps;
      if (quad == 1) dm[(size_t)t * NN + nb_ + col] = pd;
    }
  }
}

// Head-partitioned attn: head = blockIdx & 7 (round-robin -> one head slice
// per XCD L2: 1.6 MB hm + 0.4 MB sm/dm << 4 MB). One wave = 8 nodes x 1 head.
// lane = n8*8 + k8 for softmax; lane = n8*8 + u (uint pair) for gathers.
// Per-lane k-accumulation: no cross-lane reduction in the aggregation.
template <bool LAST>
__device__ inline void attn_body(
    const int* __restrict__ nb, const unsigned int* __restrict__ hm,
    const float* __restrict__ sm, const float* __restrict__ dm,
    void* __restrict__ xout) {
  const int lane = threadIdx.x & 63;
  const int h = blockIdx.x & 7;
  const int grp = (blockIdx.x >> 3) * 4 + (threadIdx.x >> 6);
  const int n0 = grp * 8;
  const int n8 = lane >> 3;                 // node within group (both layouts)
  const int k8 = lane & 7;
  const int nme = n0 + n8;
  const int nc = nme < NN ? nme : NN - 1;   // clamp reads for tail
  const int nbA = nb[(size_t)nc * KK + k8];        // r(n8, k8)
  const int nbB = nb[(size_t)nc * KK + 8 + k8];    // r(n8, k8+8)
  const unsigned int* hs = hm + (size_t)h * NN * 8;  // head slice, 8 uints/node
  // 16 gathers, all issued before softmax. Gather g covers k=g for all 8
  // nodes: lane supplies n=lane>>3, u=lane&7 -> 8 x 32B coalesced segments.
  unsigned int ug[16];
#pragma unroll
  for (int g = 0; g < 16; ++g) {
    const int src = (lane & 0x38) + (g & 7);      // n8*8 + (g&7)
    const int r = __shfl((g < 8) ? nbA : nbB, src);
    ug[g] = hs[(size_t)r * 8 + (lane & 7)];
  }
  // softmax over k for (n8, head): logits at lane n8*8+k8
  const float ss = sm[(size_t)h * NN + nc];
  float e0 = ss + dm[(size_t)h * NN + nbA];
  float e1 = ss + dm[(size_t)h * NN + nbB];
  e0 = e0 > 0.f ? e0 : 0.2f * e0;
  e1 = e1 > 0.f ? e1 : 0.2f * e1;
  float m = fmaxf(e0, e1);
  m = fmaxf(m, __shfl_xor(m, 1));
  m = fmaxf(m, __shfl_xor(m, 2));
  m = fmaxf(m, __shfl_xor(m, 4));
  float p0 = __expf(e0 - m), p1 = __expf(e1 - m);
  float s = p0 + p1;
  s += __shfl_xor(s, 1); s += __shfl_xor(s, 2); s += __shfl_xor(s, 4);
  const float inv = 1.f / s;
  p0 *= inv; p1 *= inv;
  // aggregate: lane owns (n8, dims 2u, 2u+1); sums all 16 k locally
  float a0 = 0.f, a1 = 0.f;
#pragma unroll
  for (int g = 0; g < 16; ++g) {
    const int src = (lane & 0x38) + (g & 7);
    const float w = __shfl((g < 8) ? p0 : p1, src);
    a0 = fmaf(w, __uint_as_float(ug[g] << 16), a0);
    a1 = fmaf(w, __uint_as_float(ug[g] & 0xffff0000u), a1);
  }
  const float o0 = a0 > 0.f ? a0 : __expf(a0) - 1.f;
  const float o1 = a1 > 0.f ? a1 : __expf(a1) - 1.f;
  if (nme < NN) {
    const int u = lane & 7;
    if (LAST) {
      *(float2*)((float*)xout + (size_t)nme * HID + h * 16 + 2 * u) =
          make_float2(o0, o1);
    } else {
      ((unsigned int*)xout)[(size_t)nme * (HID / 2) + h * 8 + u] =
          (unsigned)f2bf(o0) | ((unsigned)f2bf(o1) << 16);
    }
  }
}

__global__ __launch_bounds__(256) void attn0_kernel(
    const int* __restrict__ nb, const unsigned int* __restrict__ hm,
    const float* __restrict__ sm, const float* __restrict__ dm,
    unsigned short* __restrict__ xbf) {
  attn_body<false>(nb, hm, sm, dm, (void*)xbf);
}

__global__ __launch_bounds__(256) void attn1_kernel(
    const int* __restrict__ nb, const unsigned int* __restrict__ hm,
    const float* __restrict__ sm, const float* __restrict__ dm,
    float* __restrict__ out) {
  attn_body<true>(nb, hm, sm, dm, (void*)out);
}

extern "C" void kernel_launch(void* const* d_in, const int* in_sizes, int n_in,
                              void* d_out, int out_size, void* d_ws, size_t ws_size,
                              hipStream_t stream) {
  const float* feature = (const float*)d_in[0];
  const int*   nb      = (const int*)d_in[1];
  const float* pca_w   = (const float*)d_in[2];
  const float* pca_b   = (const float*)d_in[3];
  const float* Ws      = (const float*)d_in[4];
  const float* bs      = (const float*)d_in[5];
  const float* a_src   = (const float*)d_in[6];
  const float* a_dst   = (const float*)d_in[7];
  float* out = (float*)d_out;

  unsigned short* xbf = (unsigned short*)d_ws;                 // [N][128] bf16 node-major
  unsigned short* hm  = xbf + (size_t)NN * HID;                // [8][N][16] bf16 head-major
  float* sm = (float*)(hm + (size_t)HH * NN * 16);             // [8][N]
  float* dm = sm + (size_t)HH * NN;                            // [8][N]
  unsigned short* frags = (unsigned short*)(dm + (size_t)HH * NN); // 106496 shorts

  const int ntile2 = (NN / 16 + 1) / 2;          // 1563 blocks, 2 tiles/wave
  const int nattn = ((NN + 31) / 32) * 8;        // 1563 chunks x 8 heads = 12504
  prep_kernel<<<208, 256, 0, stream>>>(pca_w, Ws, frags);
  pca_mfma<<<ntile2, 64, 0, stream>>>(feature, frags, frags + 20480, pca_b, xbf);
  for (int l = 0; l < 2; ++l) {
    const unsigned short* wh = frags + 40960 + (size_t)l * 32768;
    proj_mfma<<<ntile2, 64, 0, stream>>>(
        xbf, wh, wh + 16384, bs + (size_t)l * HID,
        a_src + (size_t)l * HID, a_dst + (size_t)l * HID, hm, sm, dm);
    if (l == 1)
      attn1_kernel<<<nattn, 256, 0, stream>>>(nb, (const unsigned int*)hm,
                                              sm, dm, out);
    else
      attn0_kernel<<<nattn, 256, 0, stream>>>(nb, (const unsigned int*)hm,
                                              sm, dm, xbf);
  }
}